// Round 4
// baseline (837.424 us; speedup 1.0000x reference)
//
#include <hip/hip_runtime.h>
#include <hip/hip_cooperative_groups.h>
#include <math.h>

namespace cg = cooperative_groups;

#define T_FRAMES 24000
#define NC1 97
#define NC2 300
#define NCC 397          // NC1 + NC2
#define NA 3806
#define NA_PAD 3808      // uint4 multiple
#define NSORT 4096       // fallback global key list length
#define H_DIM 909        // 512 + 97 + 300
#define COFF 512         // offset of clogit within feature row
#define TAB 400          // padded LDS table stride (slot 397 = -INF sentinel)
#define SENT_NID 300u    // sentinel key nid -> gathers S[NC1+300] = S[397] = -INF

// ---------------- wave-level reduction helpers (no barriers) ----------------

__device__ __forceinline__ float waveMax(float v) {
#pragma unroll
    for (int off = 32; off > 0; off >>= 1) v = fmaxf(v, __shfl_xor(v, off));
    return v;
}

__device__ __forceinline__ float waveSum(float v) {
#pragma unroll
    for (int off = 32; off > 0; off >>= 1) v += __shfl_xor(v, off);
    return v;
}

// monotone float -> u32 mapping (preserves <) for packed argmax keys
__device__ __forceinline__ unsigned flip32(float f) {
    unsigned u = __float_as_uint(f);
    return (u & 0x80000000u) ? ~u : (u | 0x80000000u);
}

// ============================================================================
// MEGA KERNEL (cooperative): prep + frame stats/argmax + scan + segout
// ============================================================================

__global__ __launch_bounds__(256, 4) void k_all(
    const float* __restrict__ ff,
    const int* __restrict__ vids,
    const int* __restrict__ nids,
    int* __restrict__ pk,
    float2* __restrict__ fstats,
    int* __restrict__ pred,
    int* __restrict__ seg_start,
    int* __restrict__ blockCnt,
    int* __restrict__ blockOfs,
    int* __restrict__ Scnt,
    float* __restrict__ out)
{
    const int tid = threadIdx.x;
    const int wid = tid >> 6, lane = tid & 63;
    const int b = blockIdx.x;
    const int NBLK = gridDim.x;          // >= 512 (CH <= 47 < 64 below)
    const int NW = NBLK * 4;
    const int gw = b * 4 + wid;

    __shared__ float sh[4][TAB];         // 6.4 KB: per-wave tables
    __shared__ unsigned skey[NA_PAD];    // 15.2 KB: nid-bucketed keys (private)
    __shared__ unsigned cnt[NC2];
    __shared__ unsigned ofs[NC2];

    // ---- prep: per-block counting sort of actions by nid into LDS keys ----
    // key = nid<<19 | vid<<12 | a  (argmax reduce is order-independent)
    for (int i = tid; i < NC2; i += 256) cnt[i] = 0u;
    __syncthreads();
    for (int a = tid; a < NA; a += 256) atomicAdd(&cnt[nids[a]], 1u);
    if (b == 0) {   // pk packed once, globally (consumed only after grid syncs)
        for (int a = tid; a < NA_PAD; a += 256)
            pk[a] = (a < NA) ? (vids[a] | (nids[a] << 16)) : 0;
    }
    __syncthreads();
    if (tid < 64) {   // exclusive scan of 300 bucket counts (wave 0)
        unsigned run = 0;
        for (int c = 0; c < 5; c++) {
            int i = c * 64 + tid;
            unsigned x = (i < NC2) ? cnt[i] : 0u;
            unsigned inc = x;
#pragma unroll
            for (int d = 1; d < 64; d <<= 1) {
                unsigned y = __shfl_up(inc, d);
                if (tid >= d) inc += y;
            }
            if (i < NC2) ofs[i] = run + inc - x;
            run += __shfl(inc, 63);
        }
    }
    __syncthreads();
    for (int a = tid; a < NA; a += 256) {
        unsigned v = (unsigned)vids[a], n = (unsigned)nids[a];
        unsigned p = atomicAdd(&ofs[n], 1u);
        skey[p] = (n << 19) | (v << 12) | (unsigned)a;
    }
    for (int i = NA + tid; i < NA_PAD; i += 256) skey[i] = (SENT_NID << 19);
    __syncthreads();

    // ---- phase 1: per-frame stats + argmax (wave-private, barrier-free) ----
    float* S = sh[wid];
    const uint4* sk4 = (const uint4*)skey;

    for (int t = gw; t < T_FRAMES; t += NW) {
        const float* row = ff + (size_t)t * H_DIM + COFF;
        float xv[7];
        float vmax = -INFINITY, nmax = -INFINITY;
#pragma unroll
        for (int j = 0; j < 7; j++) {
            const int idx = lane + j * 64;
            float x = -INFINITY;
            if (idx < NCC)      { x = row[idx]; S[idx] = x; }
            else if (idx < TAB) { S[idx] = -INFINITY; }   // sentinel slots
            xv[j] = x;
            if (idx < NC1) vmax = fmaxf(vmax, x);
            else           nmax = fmaxf(nmax, x);
        }
        vmax = waveMax(vmax);
        nmax = waveMax(nmax);

        float vs = 0.f, ns = 0.f;
#pragma unroll
        for (int j = 0; j < 7; j++) {
            const int idx = lane + j * 64;
            if (idx < NC1)      vs += __expf(xv[j] - vmax);
            else if (idx < NCC) ns += __expf(xv[j] - nmax);
        }
        vs = waveSum(vs);
        ns = waveSum(ns);
        const float c1 = vmax + __logf(vs);
        const float c2 = nmax + __logf(ns);

        // argmax over raw sums (shift-invariant). padding keys hit the -INF
        // sentinel slot -> never win -> no guard branch needed.
        unsigned long long best = 0ull;
        for (int g = lane; g < NA_PAD / 4; g += 64) {     // 15 iterations
            const uint4 kq = sk4[g];
            const unsigned ks[4] = {kq.x, kq.y, kq.z, kq.w};
#pragma unroll
            for (int jj = 0; jj < 4; jj++) {
                const unsigned kk = ks[jj];
                const float val = S[(kk >> 12) & 0x7Fu] + S[NC1 + (kk >> 19)];
                const unsigned long long rk =
                    ((unsigned long long)flip32(val) << 32) | ((~kk) & 0xFFFu);
                best = (rk > best) ? rk : best;
            }
        }
#pragma unroll
        for (int off = 32; off > 0; off >>= 1) {
            unsigned long long o = __shfl_xor(best, off);
            best = (o > best) ? o : best;
        }
        if (lane == 0) {
            pred[t] = (int)((~(unsigned)best) & 0xFFFu);
            fstats[t] = make_float2(c1, c2);
        }
    }

    cg::this_grid().sync();   // pred/fstats visible grid-wide

    // ---- scan A: per-block change-flag count (wave 0, ballot) ----
    const int CH = (T_FRAMES + NBLK - 1) / NBLK;          // <= 47 for NBLK>=512
    if (wid == 0) {
        int t = b * CH + lane;
        int flag = (lane < CH && t > 0 && t < T_FRAMES) ? (pred[t] != pred[t - 1]) : 0;
        unsigned long long m = __ballot(flag);
        if (lane == 0) blockCnt[b] = __popcll(m);
    }
    cg::this_grid().sync();

    // ---- scan B: block 0 wave 0 scans block counts ----
    if (b == 0 && wid == 0) {
        int run = 0;
        const int NCHK = (NBLK + 63) / 64;
        for (int c = 0; c < NCHK; c++) {
            int i = c * 64 + lane;
            int x = (i < NBLK) ? blockCnt[i] : 0;
            int inc = x;
#pragma unroll
            for (int d = 1; d < 64; d <<= 1) {
                int y = __shfl_up(inc, d);
                if (lane >= d) inc += y;
            }
            if (i < NBLK) blockOfs[i] = run + inc - x;
            run += __shfl(inc, 63);
        }
        if (lane == 0) *Scnt = run + 1;
    }
    cg::this_grid().sync();

    // ---- scan C: emit seg_start ----
    if (wid == 0) {
        const int base = blockOfs[b];
        int t = b * CH + lane;
        int flag = (lane < CH && t > 0 && t < T_FRAMES) ? (pred[t] != pred[t - 1]) : 0;
        unsigned long long m = __ballot(flag);
        if (flag) {
            int lp_ = __popcll(m & ((1ull << lane) - 1ull));
            seg_start[base + lp_ + 1] = t;
        }
        if (b == 0 && lane == 0) seg_start[0] = 0;
    }
    cg::this_grid().sync();

    // ---- phase 3: per-segment softmax + fused output write ----
    const int S_ = *Scnt;
    const int2* pk2 = (const int2*)pk;

    for (int s = gw; s < S_; s += NW) {
        const int start = seg_start[s];
        int end = (s + 1 < S_) ? seg_start[s + 1] : T_FRAMES;
        if (end > T_FRAMES) end = T_FRAMES;
        const int len = end - start;

        float acc[7] = {0.f, 0.f, 0.f, 0.f, 0.f, 0.f, 0.f};
        const float* basep = ff + (size_t)start * H_DIM + COFF;
        for (int k = 0; k < len; k++) {
            const float* p = basep + (size_t)k * H_DIM;
#pragma unroll
            for (int j = 0; j < 7; j++) {
                const int idx = lane + j * 64;
                if (idx < NCC) acc[j] += p[idx];
            }
        }
        const float inv = 1.f / (float)len;

        float lp[7];
        float vmax = -INFINITY, nmax = -INFINITY;
#pragma unroll
        for (int j = 0; j < 7; j++) {
            const int idx = lane + j * 64;
            float x = (idx < NCC) ? acc[j] * inv : -INFINITY;
            lp[j] = x;
            if (idx < NC1) vmax = fmaxf(vmax, x);
            else           nmax = fmaxf(nmax, x);
        }
        vmax = waveMax(vmax);
        nmax = waveMax(nmax);
        float vs = 0.f, ns = 0.f;
#pragma unroll
        for (int j = 0; j < 7; j++) {
            const int idx = lane + j * 64;
            if (idx < NC1)      vs += __expf(lp[j] - vmax);
            else if (idx < NCC) ns += __expf(lp[j] - nmax);
        }
        vs = waveSum(vs);
        ns = waveSum(ns);
        const float cv = vmax + __logf(vs);
        const float cn = nmax + __logf(ns);
#pragma unroll
        for (int j = 0; j < 7; j++) {
            const int idx = lane + j * 64;
            lp[j] -= (idx < NC1) ? cv : cn;
        }

        for (int t = start; t < end; t++) {
            const float2 c = fstats[t];
            const float* row = ff + (size_t)t * H_DIM + COFF;
#pragma unroll
            for (int j = 0; j < 7; j++) {
                const int idx = lane + j * 64;
                if (idx < NCC)
                    S[idx] = row[idx] + lp[j] - ((idx < NC1) ? c.x : c.y);
            }
            // same-wave LDS ops complete in order: no barrier needed
            float* orow = out + (size_t)t * NA;
            for (int g = lane; g < NA / 2; g += 64) {
                const int2 p2 = pk2[g];
                float2 o;
                o.x = S[p2.x & 0xffff] + S[NC1 + (p2.x >> 16)];
                o.y = S[p2.y & 0xffff] + S[NC1 + (p2.y >> 16)];
                *(float2*)(orow + 2 * g) = o;
            }
        }
    }
}

// ============================================================================
// FALLBACK PATH — verbatim round-3 kernels (used only if cooperative launch
// is rejected by the runtime/graph capture)
// ============================================================================

__global__ __launch_bounds__(256) void k_prep(const int* __restrict__ vids,
                                              const int* __restrict__ nids,
                                              int* __restrict__ pk,
                                              unsigned* __restrict__ skeyg) {
    __shared__ unsigned cnt[NC2];
    __shared__ unsigned ofs[NC2];
    const int tid = threadIdx.x;

    for (int i = tid; i < NC2; i += 256) cnt[i] = 0u;
    __syncthreads();
    for (int a = tid; a < NA; a += 256) {
        int v = vids[a], n = nids[a];
        pk[a] = v | (n << 16);
        atomicAdd(&cnt[n], 1u);
    }
    __syncthreads();
    if (tid < 64) {
        unsigned run = 0;
        for (int c = 0; c < 5; c++) {
            int i = c * 64 + tid;
            unsigned x = (i < NC2) ? cnt[i] : 0u;
            unsigned inc = x;
#pragma unroll
            for (int d = 1; d < 64; d <<= 1) {
                unsigned y = __shfl_up(inc, d);
                if (tid >= d) inc += y;
            }
            if (i < NC2) ofs[i] = run + inc - x;
            run += __shfl(inc, 63);
        }
    }
    __syncthreads();
    for (int a = tid; a < NA; a += 256) {
        unsigned v = (unsigned)vids[a], n = (unsigned)nids[a];
        unsigned p = atomicAdd(&ofs[n], 1u);
        skeyg[p] = (n << 19) | (v << 12) | (unsigned)a;
    }
    for (int i = NA + tid; i < NSORT; i += 256) skeyg[i] = 0xFFFFFFFFu;
}

__global__ __launch_bounds__(256) void k_frame(const float* __restrict__ ff,
                                               const unsigned* __restrict__ skeyg,
                                               float2* __restrict__ fstats,
                                               int* __restrict__ pred) {
    const int tid = threadIdx.x;
    const int wid = tid >> 6, lane = tid & 63;
    const int t = blockIdx.x * 4 + wid;

    __shared__ float sh[4][TAB];
    float* S = sh[wid];
    const float* row = ff + (size_t)t * H_DIM + COFF;

    float xv[7];
    float vmax = -INFINITY, nmax = -INFINITY;
#pragma unroll
    for (int j = 0; j < 7; j++) {
        const int idx = lane + j * 64;
        float x = -INFINITY;
        if (idx < NCC) { x = row[idx]; S[idx] = x; }
        xv[j] = x;
        if (idx < NC1) vmax = fmaxf(vmax, x);
        else           nmax = fmaxf(nmax, x);
    }
    vmax = waveMax(vmax);
    nmax = waveMax(nmax);
    float vs = 0.f, ns = 0.f;
#pragma unroll
    for (int j = 0; j < 7; j++) {
        const int idx = lane + j * 64;
        if (idx < NC1)      vs += __expf(xv[j] - vmax);
        else if (idx < NCC) ns += __expf(xv[j] - nmax);
    }
    vs = waveSum(vs);
    ns = waveSum(ns);
    const float c1 = vmax + __logf(vs);
    const float c2 = nmax + __logf(ns);

    const uint4* sk4 = (const uint4*)skeyg;
    unsigned long long best = 0ull;
    for (int g = lane; g < NSORT / 4; g += 64) {
        const uint4 kq = sk4[g];
        const unsigned ks[4] = {kq.x, kq.y, kq.z, kq.w};
#pragma unroll
        for (int j = 0; j < 4; j++) {
            const unsigned kk = ks[j];
            if (kk != 0xFFFFFFFFu) {
                const float val = S[(kk >> 12) & 0x7Fu] + S[NC1 + (kk >> 19)];
                const unsigned long long rk =
                    ((unsigned long long)flip32(val) << 32) | ((~kk) & 0xFFFu);
                best = (rk > best) ? rk : best;
            }
        }
    }
#pragma unroll
    for (int off = 32; off > 0; off >>= 1) {
        unsigned long long o = __shfl_xor(best, off);
        best = (o > best) ? o : best;
    }
    if (lane == 0) {
        pred[t] = (int)((~(unsigned)best) & 0xFFFu);
        fstats[t] = make_float2(c1, c2);
    }
}

__global__ __launch_bounds__(1024) void k_scan(const int* __restrict__ pred,
                                               int* __restrict__ seg_start,
                                               int* __restrict__ Scount) {
    const int tid = threadIdx.x;
    __shared__ unsigned short flg[T_FRAMES];
    __shared__ int wsum[16];

    for (int t = tid; t < T_FRAMES; t += 1024)
        flg[t] = (unsigned short)((t > 0) ? (pred[t] != pred[t - 1]) : 0);
    __syncthreads();

    const int CH = (T_FRAMES + 1023) / 1024;
    const int base = tid * CH;
    int cnt = 0;
    for (int k = 0; k < CH; k++) {
        int t = base + k;
        if (t < T_FRAMES) cnt += flg[t];
    }
    const int lane = tid & 63, wid = tid >> 6;
    int inc = cnt;
#pragma unroll
    for (int d = 1; d < 64; d <<= 1) {
        int n = __shfl_up(inc, d);
        if (lane >= d) inc += n;
    }
    if (lane == 63) wsum[wid] = inc;
    __syncthreads();
    if (tid == 0) {
        int acc = 0;
        for (int i = 0; i < 16; i++) { int x = wsum[i]; wsum[i] = acc; acc += x; }
    }
    __syncthreads();
    int sid = wsum[wid] + inc - cnt;

    for (int k = 0; k < CH; k++) {
        int t = base + k;
        if (t >= T_FRAMES) break;
        if (t == 0) seg_start[0] = 0;
        else if (flg[t]) { sid++; seg_start[sid] = t; }
        if (t == T_FRAMES - 1) *Scount = sid + 1;
    }
}

__global__ __launch_bounds__(256) void k_segout(const float* __restrict__ ff,
                                                const int* __restrict__ pk,
                                                const float2* __restrict__ fstats,
                                                const int* __restrict__ seg_start,
                                                const int* __restrict__ Scount,
                                                float* __restrict__ out) {
    const int tid = threadIdx.x;
    const int wid = tid >> 6, lane = tid & 63;
    const int s = blockIdx.x * 4 + wid;
    const int S = *Scount;
    if (s >= S) return;

    const int start = seg_start[s];
    int end = (s + 1 < S) ? seg_start[s + 1] : T_FRAMES;
    if (end > T_FRAMES) end = T_FRAMES;
    const int len = end - start;

    float acc[7] = {0.f, 0.f, 0.f, 0.f, 0.f, 0.f, 0.f};
    const float* basep = ff + (size_t)start * H_DIM + COFF;
    for (int k = 0; k < len; k++) {
        const float* p = basep + (size_t)k * H_DIM;
#pragma unroll
        for (int j = 0; j < 7; j++) {
            const int idx = lane + j * 64;
            if (idx < NCC) acc[j] += p[idx];
        }
    }
    const float inv = 1.f / (float)len;

    float lp[7];
    float vmax = -INFINITY, nmax = -INFINITY;
#pragma unroll
    for (int j = 0; j < 7; j++) {
        const int idx = lane + j * 64;
        float x = (idx < NCC) ? acc[j] * inv : -INFINITY;
        lp[j] = x;
        if (idx < NC1) vmax = fmaxf(vmax, x);
        else           nmax = fmaxf(nmax, x);
    }
    vmax = waveMax(vmax);
    nmax = waveMax(nmax);
    float vs = 0.f, ns = 0.f;
#pragma unroll
    for (int j = 0; j < 7; j++) {
        const int idx = lane + j * 64;
        if (idx < NC1)      vs += __expf(lp[j] - vmax);
        else if (idx < NCC) ns += __expf(lp[j] - nmax);
    }
    vs = waveSum(vs);
    ns = waveSum(ns);
    const float cv = vmax + __logf(vs);
    const float cn = nmax + __logf(ns);
#pragma unroll
    for (int j = 0; j < 7; j++) {
        const int idx = lane + j * 64;
        lp[j] -= (idx < NC1) ? cv : cn;
    }

    __shared__ float sh[4][TAB];
    float* Stab = sh[wid];
    const int2* pk2 = (const int2*)pk;

    for (int t = start; t < end; t++) {
        const float2 c = fstats[t];
        const float* row = ff + (size_t)t * H_DIM + COFF;
#pragma unroll
        for (int j = 0; j < 7; j++) {
            const int idx = lane + j * 64;
            if (idx < NCC)
                Stab[idx] = row[idx] + lp[j] - ((idx < NC1) ? c.x : c.y);
        }
        float* orow = out + (size_t)t * NA;
        for (int g = lane; g < NA / 2; g += 64) {
            const int2 p2 = pk2[g];
            float2 o;
            o.x = Stab[p2.x & 0xffff] + Stab[NC1 + (p2.x >> 16)];
            o.y = Stab[p2.y & 0xffff] + Stab[NC1 + (p2.y >> 16)];
            *(float2*)(orow + 2 * g) = o;
        }
    }
}

// ---------------- launcher --------------------------------------------------

extern "C" void kernel_launch(void* const* d_in, const int* in_sizes, int n_in,
                              void* d_out, int out_size, void* d_ws, size_t ws_size,
                              hipStream_t stream) {
    const float* ff = (const float*)d_in[0];
    const int* vids = (const int*)d_in[1];
    const int* nids = (const int*)d_in[2];
    float* out = (float*)d_out;

    char* ws = (char*)d_ws;
    size_t off = 0;
    float2* fstats = (float2*)(ws + off);   off += (size_t)T_FRAMES * 8;   // 192000
    int* pred = (int*)(ws + off);           off += (size_t)T_FRAMES * 4;   // 96000
    int* seg_start = (int*)(ws + off);      off += (size_t)T_FRAMES * 4;   // 96000
    int* Scnt = (int*)(ws + off);           off += 16;
    int* pk = (int*)(ws + off);             off += (size_t)NA_PAD * 4;     // 15232
    int* blockCnt = (int*)(ws + off);       off += 1024 * 4;
    int* blockOfs = (int*)(ws + off);       off += 1024 * 4;
    unsigned* skeyg = (unsigned*)(ws + off); off += (size_t)NSORT * 4;     // fallback

    // grid sized for guaranteed co-residency (clamped to [512, 1024])
    static int maxb = 0;
    if (maxb == 0) {
        int q = 0;
        if (hipOccupancyMaxActiveBlocksPerMultiprocessor(&q, (const void*)k_all,
                                                         256, 0) != hipSuccess || q < 2)
            q = 2;
        if (q > 4) q = 4;
        maxb = q;
    }
    const int grid = maxb * 256;   // 512 or 1024 blocks

    void* args[] = { (void*)&ff, (void*)&vids, (void*)&nids, (void*)&pk,
                     (void*)&fstats, (void*)&pred, (void*)&seg_start,
                     (void*)&blockCnt, (void*)&blockOfs, (void*)&Scnt,
                     (void*)&out };

    hipError_t err = hipLaunchCooperativeKernel((const void*)k_all, dim3(grid),
                                                dim3(256), args, 0, stream);
    if (err != hipSuccess) {
        // fallback: round-3 four-kernel pipeline
        k_prep<<<1, 256, 0, stream>>>(vids, nids, pk, skeyg);
        k_frame<<<T_FRAMES / 4, 256, 0, stream>>>(ff, skeyg, fstats, pred);
        k_scan<<<1, 1024, 0, stream>>>(pred, seg_start, Scnt);
        k_segout<<<T_FRAMES / 4, 256, 0, stream>>>(ff, pk, fstats, seg_start, Scnt, out);
    }
}